// Round 9
// baseline (208.385 us; speedup 1.0000x reference)
//
#include <hip/hip_runtime.h>
#include <math.h>

#define N_NODES 50000
#define N_EDGES 800000
#define IN_F 256
#define OUT_F 128
#define ALPHA 0.2f

// ---- atomic-free scatter geometry ----
#define B_DST 32
#define B_EDGE 16
#define R_NODES 1563                       // ceil(N_NODES / B_DST)
#define CHUNK_E (N_EDGES / B_EDGE)         // 50000 edges per chunk
#define CAP_C 12                           // per (node,chunk); Po(1) tail P(>12)~1e-10
#define RAW_STRIDE (B_EDGE * CAP_C)        // 192 ushorts per node
#define SCAT_BLOCKS (B_DST * B_EDGE)       // 512
#define SLOT_CAP 64                        // compacted slots per node (front of raw row)

#define CONV_BLOCKS (N_NODES * IN_F / 8 / 256)   // 6250 (exact)
#define COMPACT_BLOCKS ((N_NODES + 255) / 256)   // 196
#define GEMM_WAVES ((N_NODES + 15) / 16)         // 3125: 16 rows x 128 cols per wave
#define GEMM_BLOCKS ((GEMM_WAVES + 3) / 4)       // 782

typedef short bf16x8 __attribute__((ext_vector_type(8)));
typedef float f32x4  __attribute__((ext_vector_type(4)));

static __device__ __forceinline__ unsigned short f2bf(float f) {
    unsigned int u = __float_as_uint(f);
    u += 0x7FFFu + ((u >> 16) & 1u);
    return (unsigned short)(u >> 16);
}
static __device__ __forceinline__ float bf2f(unsigned int u16) {
    return __uint_as_float(u16 << 16);
}

// ---------------- K1: atomic-free edge scatter (standalone, measurable) ---
__global__ __launch_bounds__(256, 4) void k_scat(const int* __restrict__ adj,
                                                 unsigned short* __restrict__ slots_raw,
                                                 unsigned char* __restrict__ cnt8) {
    const int b = blockIdx.x, t = threadIdx.x;
    const int j  = b % B_EDGE;         // chunk index
    const int di = b / B_EDGE;         // dst range index
    const int base = di * R_NODES;
    const int lim  = min(base + R_NODES, N_NODES);
    __shared__ int cl[R_NODES];
    for (int k = t; k < R_NODES; k += 256) cl[k] = 0;
    __syncthreads();
    const int e0 = j * CHUNK_E;
    const int4* dp = (const int4*)(adj + N_EDGES + e0);
    const int4* sp = (const int4*)(adj + e0);
    const int nit = CHUNK_E / 4;       // 12500
    for (int it0 = t; it0 < nit; it0 += 1024) {
        int4 dv[4], sv[4];
#pragma unroll
        for (int u = 0; u < 4; ++u) {
            const int it = it0 + u * 256;
            if (it < nit) { dv[u] = dp[it]; sv[u] = sp[it]; }
            else          { dv[u] = make_int4(-1, -1, -1, -1); sv[u] = make_int4(0, 0, 0, 0); }
        }
#pragma unroll
        for (int u = 0; u < 4; ++u) {
            const int4 d = dv[u], s = sv[u];
            if (d.x >= base && d.x < lim) {
                const int p = atomicAdd(&cl[d.x - base], 1);
                if (p < CAP_C) slots_raw[(size_t)d.x * RAW_STRIDE + j * CAP_C + p] = (unsigned short)s.x;
            }
            if (d.y >= base && d.y < lim) {
                const int p = atomicAdd(&cl[d.y - base], 1);
                if (p < CAP_C) slots_raw[(size_t)d.y * RAW_STRIDE + j * CAP_C + p] = (unsigned short)s.y;
            }
            if (d.z >= base && d.z < lim) {
                const int p = atomicAdd(&cl[d.z - base], 1);
                if (p < CAP_C) slots_raw[(size_t)d.z * RAW_STRIDE + j * CAP_C + p] = (unsigned short)s.z;
            }
            if (d.w >= base && d.w < lim) {
                const int p = atomicAdd(&cl[d.w - base], 1);
                if (p < CAP_C) slots_raw[(size_t)d.w * RAW_STRIDE + j * CAP_C + p] = (unsigned short)s.w;
            }
        }
    }
    __syncthreads();
    for (int k = t; k < lim - base; k += 256)
        cnt8[(size_t)(base + k) * B_EDGE + j] = (unsigned char)min(cl[k], CAP_C);
}

// ---------------- K2: WbT transpose + h -> bf16 stream convert ----------
// blocks [0,128): WbT[n][k] = bf16(W[k][n]).
// blocks [128, 128+6250): hb = bf16(h), 8 floats/thread, fully coalesced.
__global__ __launch_bounds__(256) void k_prep2(const float* __restrict__ W,
                                               const float* __restrict__ h,
                                               unsigned short* __restrict__ WbT,
                                               unsigned short* __restrict__ hb) {
    const int b = blockIdx.x, t = threadIdx.x;
    if (b < OUT_F) {
        WbT[(size_t)b * IN_F + t] = f2bf(W[(size_t)t * OUT_F + b]);
        return;
    }
    const size_t base = ((size_t)(b - OUT_F) * 256 + t) * 8;
    const float4* hp = (const float4*)(h + base);
    const float4 x0 = hp[0], x1 = hp[1];
    bf16x8 v;
    v[0] = (short)f2bf(x0.x); v[1] = (short)f2bf(x0.y);
    v[2] = (short)f2bf(x0.z); v[3] = (short)f2bf(x0.w);
    v[4] = (short)f2bf(x1.x); v[5] = (short)f2bf(x1.y);
    v[6] = (short)f2bf(x1.z); v[7] = (short)f2bf(x1.w);
    *(bf16x8*)(hb + base) = v;
}

// ---------------- K3: fused compact + bf16 GEMM with score epilogue ------
// blocks [0,196): in-place CSR compaction (cursor proof: R6).
// blocks [196,978): GEMM, wave = 16 rows x 128 cols, K=256. hb frags (8x16B)
// preloaded (32 VGPR — fits). Scores computed from the f32 accumulator:
// s1[row] = sum_col acc*a[col], s2 = sum_col acc*a[OUT_F+col], reduced over
// grp with the verified shfl_xor(16/32) pattern.
__global__ __launch_bounds__(256, 4) void k_gemm(const unsigned short* __restrict__ hb,
                                                 const unsigned short* __restrict__ WbT,
                                                 const float* __restrict__ a,
                                                 unsigned short* __restrict__ Whb,
                                                 float* __restrict__ s_src,
                                                 float* __restrict__ s_dst,
                                                 unsigned short* __restrict__ slots_raw,
                                                 const unsigned char* __restrict__ cnt8,
                                                 int* __restrict__ cntT) {
    const int b = blockIdx.x;
    if (b < COMPACT_BLOCKS) {
        const int node = b * 256 + threadIdx.x;
        if (node >= N_NODES) return;
        const unsigned char* c8 = cnt8 + (size_t)node * B_EDGE;
        unsigned short* row = slots_raw + (size_t)node * RAW_STRIDE;
        int total = 0;
#pragma unroll
        for (int c = 0; c < B_EDGE; ++c) {
            const int dc = c8[c];
            const unsigned short* s = row + c * CAP_C;
            for (int k = 0; k < dc; ++k) {
                const unsigned short v = s[k];
                if (total < SLOT_CAP) row[total++] = v;
            }
        }
        cntT[node] = total;
        return;
    }
    // -------- GEMM role --------
    const int gid = b - COMPACT_BLOCKS;
    const int wid = gid * 4 + (threadIdx.x >> 6);
    if (wid >= GEMM_WAVES) return;
    const int lane = threadIdx.x & 63;
    const int m = lane & 15, grp = lane >> 4;
    const int row = wid * 16 + m;             // < 50000 (3125*16 exact)
    const unsigned short* hrow = hb + (size_t)row * IN_F + grp * 8;
    const unsigned short* wbase = WbT + (size_t)m * IN_F + grp * 8;

    // preload all 8 independent A-fragments (16B each, 32 VGPR)
    bf16x8 hf[8];
#pragma unroll
    for (int kt = 0; kt < 8; ++kt) hf[kt] = *(const bf16x8*)(hrow + kt * 32);

    f32x4 acc[8];
#pragma unroll
    for (int nt = 0; nt < 8; ++nt) acc[nt] = (f32x4){0.f, 0.f, 0.f, 0.f};
#pragma unroll
    for (int kt = 0; kt < 8; ++kt) {
#pragma unroll
        for (int nt = 0; nt < 8; ++nt) {
            bf16x8 wf = *(const bf16x8*)(wbase + (size_t)nt * 16 * IN_F + kt * 32);
            acc[nt] = __builtin_amdgcn_mfma_f32_16x16x32_bf16(wf, hf[kt], acc[nt], 0, 0, 0);
        }
    }

    // score epilogue from f32 accumulator
    float s1 = 0.0f, s2 = 0.0f;
#pragma unroll
    for (int nt = 0; nt < 8; ++nt) {
        const float4 a1 = *(const float4*)(a + nt * 16 + grp * 4);
        const float4 a2 = *(const float4*)(a + OUT_F + nt * 16 + grp * 4);
        const f32x4 v = acc[nt];
        s1 = fmaf(v[0], a1.x, fmaf(v[1], a1.y, fmaf(v[2], a1.z, fmaf(v[3], a1.w, s1))));
        s2 = fmaf(v[0], a2.x, fmaf(v[1], a2.y, fmaf(v[2], a2.z, fmaf(v[3], a2.w, s2))));
    }
    s1 += __shfl_xor(s1, 16); s1 += __shfl_xor(s1, 32);
    s2 += __shfl_xor(s2, 16); s2 += __shfl_xor(s2, 32);
    if (grp == 0) { s_src[row] = s1; s_dst[row] = s2; }

    unsigned short* orow = Whb + (size_t)row * OUT_F;
#pragma unroll
    for (int nt = 0; nt < 8; ++nt) {
        f32x4 v = acc[nt];
        ushort4 pk;
        pk.x = f2bf(v[0]); pk.y = f2bf(v[1]);
        pk.z = f2bf(v[2]); pk.w = f2bf(v[3]);
        *(ushort4*)(orow + nt * 16 + grp * 4) = pk;
    }
}

// ---------------- K4: CSR gather, 8-edge batches, shuffle-free ----------
__global__ __launch_bounds__(256, 4) void k_gather(const unsigned short* __restrict__ Whb,
                                                   const int* __restrict__ cntT,
                                                   const unsigned short* __restrict__ slots_raw,
                                                   const float* __restrict__ s_src,
                                                   const float* __restrict__ s_dst,
                                                   float* __restrict__ out) {
    const int wid  = (blockIdx.x * blockDim.x + threadIdx.x) >> 6;
    const int lane = threadIdx.x & 63;
    const int grp  = lane >> 4;        // 0..3: node within quad
    const int l    = lane & 15;        // 16 lanes x 16B = 256B bf16 row
    const int node = wid * 4 + grp;
    if (node >= N_NODES) return;

    const float sd = s_dst[node];
    float s0 = sd + s_src[node];
    float lr0 = (s0 > 0.0f) ? s0 : ALPHA * s0;
    float x0 = __expf(lr0);
    uint4 w0 = ((const uint4*)(Whb + (size_t)node * OUT_F))[l];
    float a0 = x0 * bf2f(w0.x & 0xFFFFu);
    float a1 = x0 * bf2f(w0.x >> 16);
    float a2 = x0 * bf2f(w0.y & 0xFFFFu);
    float a3 = x0 * bf2f(w0.y >> 16);
    float a4 = x0 * bf2f(w0.z & 0xFFFFu);
    float a5 = x0 * bf2f(w0.z >> 16);
    float a6 = x0 * bf2f(w0.w & 0xFFFFu);
    float a7 = x0 * bf2f(w0.w >> 16);
    float dsum = x0;

    const int deg = min(cntT[node], SLOT_CAP);
    const unsigned short* __restrict__ srow = slots_raw + (size_t)node * RAW_STRIDE;

    for (int i = 0; i < deg; i += 8) {
        const uint4 q = *(const uint4*)(srow + i);   // 8 ushort srcs (16B)
        unsigned su[8];
        su[0] = q.x & 0xFFFFu; su[1] = q.x >> 16;
        su[2] = q.y & 0xFFFFu; su[3] = q.y >> 16;
        su[4] = q.z & 0xFFFFu; su[5] = q.z >> 16;
        su[6] = q.w & 0xFFFFu; su[7] = q.w >> 16;
#pragma unroll
        for (int j = 0; j < 8; ++j)
            su[j] = (i + j < deg) ? min(su[j], N_NODES - 1u) : (unsigned)node;
        float e[8];
#pragma unroll
        for (int j = 0; j < 8; ++j) e[j] = sd + s_src[su[j]];
        uint4 v[8];
#pragma unroll
        for (int j = 0; j < 8; ++j) v[j] = ((const uint4*)(Whb + (size_t)su[j] * OUT_F))[l];
        float x[8];
#pragma unroll
        for (int j = 0; j < 8; ++j) {
            float lr = (e[j] > 0.0f) ? e[j] : ALPHA * e[j];
            float xv = __expf(lr);
            x[j] = (i + j < deg) ? xv : 0.0f;
        }
#pragma unroll
        for (int j = 0; j < 8; ++j) dsum += x[j];
#pragma unroll
        for (int j = 0; j < 8; ++j) {
            a0 = fmaf(x[j], bf2f(v[j].x & 0xFFFFu), a0);
            a1 = fmaf(x[j], bf2f(v[j].x >> 16), a1);
            a2 = fmaf(x[j], bf2f(v[j].y & 0xFFFFu), a2);
            a3 = fmaf(x[j], bf2f(v[j].y >> 16), a3);
            a4 = fmaf(x[j], bf2f(v[j].z & 0xFFFFu), a4);
            a5 = fmaf(x[j], bf2f(v[j].z >> 16), a5);
            a6 = fmaf(x[j], bf2f(v[j].w & 0xFFFFu), a6);
            a7 = fmaf(x[j], bf2f(v[j].w >> 16), a7);
        }
    }

    const float inv = 1.0f / dsum;
    float4 o0, o1;
    o0.x = a0 * inv; o0.y = a1 * inv; o0.z = a2 * inv; o0.w = a3 * inv;
    o1.x = a4 * inv; o1.y = a5 * inv; o1.z = a6 * inv; o1.w = a7 * inv;
    o0.x = (o0.x > 0.0f) ? o0.x : expm1f(o0.x);
    o0.y = (o0.y > 0.0f) ? o0.y : expm1f(o0.y);
    o0.z = (o0.z > 0.0f) ? o0.z : expm1f(o0.z);
    o0.w = (o0.w > 0.0f) ? o0.w : expm1f(o0.w);
    o1.x = (o1.x > 0.0f) ? o1.x : expm1f(o1.x);
    o1.y = (o1.y > 0.0f) ? o1.y : expm1f(o1.y);
    o1.z = (o1.z > 0.0f) ? o1.z : expm1f(o1.z);
    o1.w = (o1.w > 0.0f) ? o1.w : expm1f(o1.w);
    float4* op = (float4*)(out + (size_t)node * OUT_F + l * 8);
    op[0] = o0;
    op[1] = o1;
}

// ---------------- launcher ----------------
extern "C" void kernel_launch(void* const* d_in, const int* in_sizes, int n_in,
                              void* d_out, int out_size, void* d_ws, size_t ws_size,
                              hipStream_t stream) {
    const float* h   = (const float*)d_in[0];
    const int*   adj = (const int*)d_in[1];
    const float* W   = (const float*)d_in[2];
    const float* a   = (const float*)d_in[3];
    float* out = (float*)d_out;

    // workspace layout (256B-aligned chunks), total ~59MB
    char* ws = (char*)d_ws;
    const size_t SZ_WHB  = (size_t)N_NODES * OUT_F * 2;             // 12,800,000
    const size_t SZ_N    = 200704;                                  // >= N_NODES*4
    const size_t SZ_C8   = 802816;                                  // >= N_NODES*16 uchar
    const size_t SZ_RAW  = (size_t)N_NODES * RAW_STRIDE * 2;        // 19,200,000
    unsigned short* Whb   = (unsigned short*)(ws);
    float* s_src          = (float*)(ws + SZ_WHB);
    float* s_dst          = (float*)(ws + SZ_WHB + SZ_N);
    int*   cntT           = (int*)  (ws + SZ_WHB + 2 * SZ_N);
    unsigned short* WbT   = (unsigned short*)(ws + SZ_WHB + 3 * SZ_N);             // 64KB
    unsigned char* cnt8   = (unsigned char*)(ws + SZ_WHB + 3 * SZ_N + 65536);
    unsigned short* slots_raw = (unsigned short*)(ws + SZ_WHB + 3 * SZ_N + 65536 + SZ_C8);
    unsigned short* hb    = (unsigned short*)(ws + SZ_WHB + 3 * SZ_N + 65536 + SZ_C8 + SZ_RAW); // 25.6MB

    (void)in_sizes; (void)n_in; (void)out_size; (void)ws_size;

    k_scat  <<<SCAT_BLOCKS, 256, 0, stream>>>(adj, slots_raw, cnt8);
    k_prep2 <<<OUT_F + CONV_BLOCKS, 256, 0, stream>>>(W, h, WbT, hb);
    k_gemm  <<<COMPACT_BLOCKS + GEMM_BLOCKS, 256, 0, stream>>>(hb, WbT, a, Whb,
                                                               s_src, s_dst,
                                                               slots_raw, cnt8, cntT);
    k_gather<<<(N_NODES / 4 * 64) / 256, 256, 0, stream>>>(Whb, cntT, slots_raw,
                                                           s_src, s_dst, out);
}

// Round 10
// 201.270 us; speedup vs baseline: 1.0353x; 1.0353x over previous
//
#include <hip/hip_runtime.h>
#include <math.h>

#define N_NODES 50000
#define N_EDGES 800000
#define IN_F 256
#define OUT_F 128
#define ALPHA 0.2f

// ---- atomic-free scatter geometry (B_EDGE doubled for TLP) ----
#define B_DST 32
#define B_EDGE 32
#define R_NODES 1563                       // ceil(N_NODES / B_DST)
#define CHUNK_E (N_EDGES / B_EDGE)         // 25000 edges per chunk
#define CAP_C 10                           // per (node,chunk); Po(0.5) tail ~1e-11/bin
#define RAW_STRIDE (B_EDGE * CAP_C)        // 320 ushorts per node (640B, 16B-aligned)
#define SCAT_BLOCKS (B_DST * B_EDGE)       // 1024
#define SLOT_CAP 64                        // compacted slots per node (front of raw row)

#define CONV_BLOCKS (N_NODES * IN_F / 8 / 256)   // 6250 (exact)
#define COMPACT_BLOCKS ((N_NODES + 255) / 256)   // 196
#define GEMM_BLOCKS ((N_NODES + 63) / 64)        // 782: 64 rows/block, 4 waves
#define GEMM_WAVES_TOT (GEMM_BLOCKS * 4)

typedef short bf16x8 __attribute__((ext_vector_type(8)));
typedef float f32x4  __attribute__((ext_vector_type(4)));

static __device__ __forceinline__ unsigned short f2bf(float f) {
    unsigned int u = __float_as_uint(f);
    u += 0x7FFFu + ((u >> 16) & 1u);
    return (unsigned short)(u >> 16);
}
static __device__ __forceinline__ float bf2f(unsigned int u16) {
    return __uint_as_float(u16 << 16);
}

// ---------------- K1: atomic-free edge scatter ----------------
// 1024 blocks (4/CU) — R9's 49us was TLP-starved at 512 blocks/16% occ.
__global__ __launch_bounds__(256, 4) void k_scat(const int* __restrict__ adj,
                                                 unsigned short* __restrict__ slots_raw,
                                                 unsigned char* __restrict__ cnt8) {
    const int b = blockIdx.x, t = threadIdx.x;
    const int j  = b % B_EDGE;         // chunk index
    const int di = b / B_EDGE;         // dst range index
    const int base = di * R_NODES;
    const int lim  = min(base + R_NODES, N_NODES);
    __shared__ int cl[R_NODES];
    for (int k = t; k < R_NODES; k += 256) cl[k] = 0;
    __syncthreads();
    const int e0 = j * CHUNK_E;
    const int4* dp = (const int4*)(adj + N_EDGES + e0);
    const int4* sp = (const int4*)(adj + e0);
    const int nit = CHUNK_E / 4;       // 6250
    for (int it0 = t; it0 < nit; it0 += 1024) {
        int4 dv[4], sv[4];
#pragma unroll
        for (int u = 0; u < 4; ++u) {
            const int it = it0 + u * 256;
            if (it < nit) { dv[u] = dp[it]; sv[u] = sp[it]; }
            else          { dv[u] = make_int4(-1, -1, -1, -1); sv[u] = make_int4(0, 0, 0, 0); }
        }
#pragma unroll
        for (int u = 0; u < 4; ++u) {
            const int4 d = dv[u], s = sv[u];
            if (d.x >= base && d.x < lim) {
                const int p = atomicAdd(&cl[d.x - base], 1);
                if (p < CAP_C) slots_raw[(size_t)d.x * RAW_STRIDE + j * CAP_C + p] = (unsigned short)s.x;
            }
            if (d.y >= base && d.y < lim) {
                const int p = atomicAdd(&cl[d.y - base], 1);
                if (p < CAP_C) slots_raw[(size_t)d.y * RAW_STRIDE + j * CAP_C + p] = (unsigned short)s.y;
            }
            if (d.z >= base && d.z < lim) {
                const int p = atomicAdd(&cl[d.z - base], 1);
                if (p < CAP_C) slots_raw[(size_t)d.z * RAW_STRIDE + j * CAP_C + p] = (unsigned short)s.z;
            }
            if (d.w >= base && d.w < lim) {
                const int p = atomicAdd(&cl[d.w - base], 1);
                if (p < CAP_C) slots_raw[(size_t)d.w * RAW_STRIDE + j * CAP_C + p] = (unsigned short)s.w;
            }
        }
    }
    __syncthreads();
    for (int k = t; k < lim - base; k += 256)
        cnt8[(size_t)(base + k) * B_EDGE + j] = (unsigned char)min(cl[k], CAP_C);
}

// ---------------- K2: WbT transpose + h -> bf16 stream convert ----------
__global__ __launch_bounds__(256) void k_prep2(const float* __restrict__ W,
                                               const float* __restrict__ h,
                                               unsigned short* __restrict__ WbT,
                                               unsigned short* __restrict__ hb) {
    const int b = blockIdx.x, t = threadIdx.x;
    if (b < OUT_F) {
        WbT[(size_t)b * IN_F + t] = f2bf(W[(size_t)t * OUT_F + b]);
        return;
    }
    const size_t base = ((size_t)(b - OUT_F) * 256 + t) * 8;
    const float4* hp = (const float4*)(h + base);
    const float4 x0 = hp[0], x1 = hp[1];
    bf16x8 v;
    v[0] = (short)f2bf(x0.x); v[1] = (short)f2bf(x0.y);
    v[2] = (short)f2bf(x0.z); v[3] = (short)f2bf(x0.w);
    v[4] = (short)f2bf(x1.x); v[5] = (short)f2bf(x1.y);
    v[6] = (short)f2bf(x1.z); v[7] = (short)f2bf(x1.w);
    *(bf16x8*)(hb + base) = v;
}

// ---------------- K3: fused compact + LDS-staged bf16 GEMM ----------
// blocks [0,196): in-place CSR compaction (cursor proof R6).
// blocks [196,978): block = 4 waves x 64 rows x 128 cols. WbT (64KB) staged
// ONCE per block into XOR-swizzled LDS: slot(col,k8) at col*32 + (k8^(col&7))
// -> 16-lane ds_read_b128 hits <=2-way banks (free, m136). Kills R9's
// per-wave 64KB L2 re-read (200MB -> 50MB) and the 56-VGPR serialization.
__global__ __launch_bounds__(256, 2) void k_gemm(const unsigned short* __restrict__ hb,
                                                 const unsigned short* __restrict__ WbT,
                                                 const float* __restrict__ a,
                                                 unsigned short* __restrict__ Whb,
                                                 float* __restrict__ s_src,
                                                 float* __restrict__ s_dst,
                                                 unsigned short* __restrict__ slots_raw,
                                                 const unsigned char* __restrict__ cnt8,
                                                 int* __restrict__ cntT) {
    const int b = blockIdx.x;
    if (b < COMPACT_BLOCKS) {
        const int node = b * 256 + threadIdx.x;
        if (node >= N_NODES) return;
        const unsigned char* c8 = cnt8 + (size_t)node * B_EDGE;
        unsigned short* row = slots_raw + (size_t)node * RAW_STRIDE;
        int total = 0;
#pragma unroll
        for (int c = 0; c < B_EDGE; ++c) {
            const int dc = c8[c];
            const unsigned short* s = row + c * CAP_C;
            for (int k = 0; k < dc; ++k) {
                const unsigned short v = s[k];
                if (total < SLOT_CAP) row[total++] = v;
            }
        }
        cntT[node] = total;
        return;
    }
    // -------- GEMM role --------
    __shared__ unsigned short wlds[32768];   // 64KB: 4096 slots x 16B
    const int t = threadIdx.x;
    // stage WbT -> LDS (swizzled), coalesced global reads
    for (int s = t; s < 4096; s += 256) {
        const int col = s >> 5, k8 = s & 31;
        const bf16x8 v = *(const bf16x8*)(WbT + (size_t)col * IN_F + k8 * 8);
        *(bf16x8*)(wlds + ((size_t)col * 32 + (k8 ^ (col & 7))) * 8) = v;
    }
    __syncthreads();

    const int gid = b - COMPACT_BLOCKS;
    const int w = t >> 6;                    // wave 0..3
    const int lane = t & 63;
    const int m = lane & 15, grp = lane >> 4;
    const int row = gid * 64 + w * 16 + m;
    const int rowc = min(row, N_NODES - 1);  // clamp loads; stores guarded
    const unsigned short* hrow = hb + (size_t)rowc * IN_F + grp * 8;

    bf16x8 hf[8];
#pragma unroll
    for (int kt = 0; kt < 8; ++kt) hf[kt] = *(const bf16x8*)(hrow + kt * 32);

    f32x4 acc[8];
#pragma unroll
    for (int nt = 0; nt < 8; ++nt) acc[nt] = (f32x4){0.f, 0.f, 0.f, 0.f};
#pragma unroll
    for (int kt = 0; kt < 8; ++kt) {
#pragma unroll
        for (int nt = 0; nt < 8; ++nt) {
            const int col = nt * 16 + m;
            const int k8 = kt * 4 + grp;
            const bf16x8 wf = *(const bf16x8*)(wlds + ((size_t)col * 32 + (k8 ^ (col & 7))) * 8);
            acc[nt] = __builtin_amdgcn_mfma_f32_16x16x32_bf16(wf, hf[kt], acc[nt], 0, 0, 0);
        }
    }

    // score epilogue from f32 accumulator
    float s1 = 0.0f, s2 = 0.0f;
#pragma unroll
    for (int nt = 0; nt < 8; ++nt) {
        const float4 a1 = *(const float4*)(a + nt * 16 + grp * 4);
        const float4 a2 = *(const float4*)(a + OUT_F + nt * 16 + grp * 4);
        const f32x4 v = acc[nt];
        s1 = fmaf(v[0], a1.x, fmaf(v[1], a1.y, fmaf(v[2], a1.z, fmaf(v[3], a1.w, s1))));
        s2 = fmaf(v[0], a2.x, fmaf(v[1], a2.y, fmaf(v[2], a2.z, fmaf(v[3], a2.w, s2))));
    }
    s1 += __shfl_xor(s1, 16); s1 += __shfl_xor(s1, 32);
    s2 += __shfl_xor(s2, 16); s2 += __shfl_xor(s2, 32);
    if (row < N_NODES) {
        if (grp == 0) { s_src[row] = s1; s_dst[row] = s2; }
        unsigned short* orow = Whb + (size_t)row * OUT_F;
#pragma unroll
        for (int nt = 0; nt < 8; ++nt) {
            f32x4 v = acc[nt];
            ushort4 pk;
            pk.x = f2bf(v[0]); pk.y = f2bf(v[1]);
            pk.z = f2bf(v[2]); pk.w = f2bf(v[3]);
            *(ushort4*)(orow + nt * 16 + grp * 4) = pk;
        }
    }
}

// ---------------- K4: CSR gather, 8-edge batches, shuffle-free ----------
__global__ __launch_bounds__(256, 4) void k_gather(const unsigned short* __restrict__ Whb,
                                                   const int* __restrict__ cntT,
                                                   const unsigned short* __restrict__ slots_raw,
                                                   const float* __restrict__ s_src,
                                                   const float* __restrict__ s_dst,
                                                   float* __restrict__ out) {
    const int wid  = (blockIdx.x * blockDim.x + threadIdx.x) >> 6;
    const int lane = threadIdx.x & 63;
    const int grp  = lane >> 4;        // 0..3: node within quad
    const int l    = lane & 15;        // 16 lanes x 16B = 256B bf16 row
    const int node = wid * 4 + grp;
    if (node >= N_NODES) return;

    const float sd = s_dst[node];
    float s0 = sd + s_src[node];
    float lr0 = (s0 > 0.0f) ? s0 : ALPHA * s0;
    float x0 = __expf(lr0);
    uint4 w0 = ((const uint4*)(Whb + (size_t)node * OUT_F))[l];
    float a0 = x0 * bf2f(w0.x & 0xFFFFu);
    float a1 = x0 * bf2f(w0.x >> 16);
    float a2 = x0 * bf2f(w0.y & 0xFFFFu);
    float a3 = x0 * bf2f(w0.y >> 16);
    float a4 = x0 * bf2f(w0.z & 0xFFFFu);
    float a5 = x0 * bf2f(w0.z >> 16);
    float a6 = x0 * bf2f(w0.w & 0xFFFFu);
    float a7 = x0 * bf2f(w0.w >> 16);
    float dsum = x0;

    const int deg = min(cntT[node], SLOT_CAP);
    const unsigned short* __restrict__ srow = slots_raw + (size_t)node * RAW_STRIDE;

    for (int i = 0; i < deg; i += 8) {
        const uint4 q = *(const uint4*)(srow + i);   // 8 ushort srcs (16B)
        unsigned su[8];
        su[0] = q.x & 0xFFFFu; su[1] = q.x >> 16;
        su[2] = q.y & 0xFFFFu; su[3] = q.y >> 16;
        su[4] = q.z & 0xFFFFu; su[5] = q.z >> 16;
        su[6] = q.w & 0xFFFFu; su[7] = q.w >> 16;
#pragma unroll
        for (int j = 0; j < 8; ++j)
            su[j] = (i + j < deg) ? min(su[j], N_NODES - 1u) : (unsigned)node;
        float e[8];
#pragma unroll
        for (int j = 0; j < 8; ++j) e[j] = sd + s_src[su[j]];
        uint4 v[8];
#pragma unroll
        for (int j = 0; j < 8; ++j) v[j] = ((const uint4*)(Whb + (size_t)su[j] * OUT_F))[l];
        float x[8];
#pragma unroll
        for (int j = 0; j < 8; ++j) {
            float lr = (e[j] > 0.0f) ? e[j] : ALPHA * e[j];
            float xv = __expf(lr);
            x[j] = (i + j < deg) ? xv : 0.0f;
        }
#pragma unroll
        for (int j = 0; j < 8; ++j) dsum += x[j];
#pragma unroll
        for (int j = 0; j < 8; ++j) {
            a0 = fmaf(x[j], bf2f(v[j].x & 0xFFFFu), a0);
            a1 = fmaf(x[j], bf2f(v[j].x >> 16), a1);
            a2 = fmaf(x[j], bf2f(v[j].y & 0xFFFFu), a2);
            a3 = fmaf(x[j], bf2f(v[j].y >> 16), a3);
            a4 = fmaf(x[j], bf2f(v[j].z & 0xFFFFu), a4);
            a5 = fmaf(x[j], bf2f(v[j].z >> 16), a5);
            a6 = fmaf(x[j], bf2f(v[j].w & 0xFFFFu), a6);
            a7 = fmaf(x[j], bf2f(v[j].w >> 16), a7);
        }
    }

    const float inv = 1.0f / dsum;
    float4 o0, o1;
    o0.x = a0 * inv; o0.y = a1 * inv; o0.z = a2 * inv; o0.w = a3 * inv;
    o1.x = a4 * inv; o1.y = a5 * inv; o1.z = a6 * inv; o1.w = a7 * inv;
    o0.x = (o0.x > 0.0f) ? o0.x : expm1f(o0.x);
    o0.y = (o0.y > 0.0f) ? o0.y : expm1f(o0.y);
    o0.z = (o0.z > 0.0f) ? o0.z : expm1f(o0.z);
    o0.w = (o0.w > 0.0f) ? o0.w : expm1f(o0.w);
    o1.x = (o1.x > 0.0f) ? o1.x : expm1f(o1.x);
    o1.y = (o1.y > 0.0f) ? o1.y : expm1f(o1.y);
    o1.z = (o1.z > 0.0f) ? o1.z : expm1f(o1.z);
    o1.w = (o1.w > 0.0f) ? o1.w : expm1f(o1.w);
    float4* op = (float4*)(out + (size_t)node * OUT_F + l * 8);
    op[0] = o0;
    op[1] = o1;
}

// ---------------- launcher ----------------
extern "C" void kernel_launch(void* const* d_in, const int* in_sizes, int n_in,
                              void* d_out, int out_size, void* d_ws, size_t ws_size,
                              hipStream_t stream) {
    const float* h   = (const float*)d_in[0];
    const int*   adj = (const int*)d_in[1];
    const float* W   = (const float*)d_in[2];
    const float* a   = (const float*)d_in[3];
    float* out = (float*)d_out;

    // workspace layout (256B-aligned chunks), total ~72.7MB
    char* ws = (char*)d_ws;
    const size_t SZ_WHB  = (size_t)N_NODES * OUT_F * 2;             // 12,800,000
    const size_t SZ_N    = 200704;                                  // >= N_NODES*4
    const size_t SZ_C8   = (size_t)N_NODES * B_EDGE;                // 1,600,000 (256-mult)
    const size_t SZ_RAW  = (size_t)N_NODES * RAW_STRIDE * 2;        // 32,000,000
    unsigned short* Whb   = (unsigned short*)(ws);
    float* s_src          = (float*)(ws + SZ_WHB);
    float* s_dst          = (float*)(ws + SZ_WHB + SZ_N);
    int*   cntT           = (int*)  (ws + SZ_WHB + 2 * SZ_N);
    unsigned short* WbT   = (unsigned short*)(ws + SZ_WHB + 3 * SZ_N);             // 64KB
    unsigned char* cnt8   = (unsigned char*)(ws + SZ_WHB + 3 * SZ_N + 65536);
    unsigned short* slots_raw = (unsigned short*)(ws + SZ_WHB + 3 * SZ_N + 65536 + SZ_C8);
    unsigned short* hb    = (unsigned short*)(ws + SZ_WHB + 3 * SZ_N + 65536 + SZ_C8 + SZ_RAW); // 25.6MB

    (void)in_sizes; (void)n_in; (void)out_size; (void)ws_size;

    k_scat  <<<SCAT_BLOCKS, 256, 0, stream>>>(adj, slots_raw, cnt8);
    k_prep2 <<<OUT_F + CONV_BLOCKS, 256, 0, stream>>>(W, h, WbT, hb);
    k_gemm  <<<COMPACT_BLOCKS + GEMM_BLOCKS, 256, 0, stream>>>(hb, WbT, a, Whb,
                                                               s_src, s_dst,
                                                               slots_raw, cnt8, cntT);
    k_gather<<<(N_NODES / 4 * 64) / 256, 256, 0, stream>>>(Whb, cntT, slots_raw,
                                                           s_src, s_dst, out);
}